// Round 1
// baseline (1497.366 us; speedup 1.0000x reference)
//
#include <hip/hip_runtime.h>

#define N_OSC 50
#define N_PER 40
#define DT 0.01f
#define STEPS 100
#define BATCH 8192
#define OG 8   // oscillator groups in phase A

// ws layout (float offsets)
#define WS_PC     0        // 50*240 = 12000 packed consts
#define WS_DIRECT 12288    // 8192
#define WS_O0     20480    // 100*8192
#define WS_TPART  839680   // OG*100*8192

// ---------------------------------------------------------------------------
// Pack per-(osc,n) constants into AoS pairs: for each osc, 20 chunks of 12:
// [e0x,e0y, e1x,e1y, obx,oby, d0x,d0y, d1x,d1y, w4x,w4y]
// ---------------------------------------------------------------------------
__global__ void pack_consts(const float* __restrict__ enc,
                            const float* __restrict__ obias,
                            const float* __restrict__ dec,
                            const float* __restrict__ fc4_w,
                            float* __restrict__ pc) {
    int idx = blockIdx.x * blockDim.x + threadIdx.x;
    if (idx >= N_OSC * N_PER) return;
    int o = idx / N_PER, n = idx % N_PER;
    int n2 = n >> 1, h = n & 1;
    float* base = pc + o * 240 + n2 * 12;
    base[0 + h]  = enc[o * 80 + 2 * n + 0];
    base[2 + h]  = enc[o * 80 + 2 * n + 1];
    base[4 + h]  = obias[o * 40 + n];
    base[6 + h]  = dec[o * 80 + n];          // dec[o][0][n]
    base[8 + h]  = dec[o * 80 + 40 + n];     // dec[o][1][n]
    base[10 + h] = fc4_w[o * 40 + n];
}

// ---------------------------------------------------------------------------
// MLP prologue: h = relu(fc1), direct = fcd(h), h2 = relu(fc2 h), x3 = fc3 h2
// Block = 256 threads handles 64 batch elements.
// ---------------------------------------------------------------------------
__global__ __launch_bounds__(256) void mlp_kernel(
    const float* __restrict__ x,
    const float* __restrict__ fc1_w, const float* __restrict__ fc1_b,
    const float* __restrict__ fc2_w, const float* __restrict__ fc2_b,
    const float* __restrict__ fc3_w, const float* __restrict__ fc3_b,
    const float* __restrict__ fcd_w, const float* __restrict__ fcd_b,
    float* __restrict__ o0out, float* __restrict__ directout) {
    __shared__ float hs[64 * 129];
    __shared__ float h2s[64 * 129];
    int tid = threadIdx.x;
    int b0 = blockIdx.x * 64;

    // h (relu(fc1 x + b1)) : 64x128 outputs
    for (int idx = tid; idx < 64 * 128; idx += 256) {
        int bb = idx >> 7, j = idx & 127;
        float x0 = x[(b0 + bb) * 2], x1 = x[(b0 + bb) * 2 + 1];
        float v = fmaf(x0, fc1_w[j * 2], fmaf(x1, fc1_w[j * 2 + 1], fc1_b[j]));
        hs[bb * 129 + j] = fmaxf(v, 0.f);
    }
    __syncthreads();

    // direct = h . fcd_w + fcd_b (one thread per b)
    if (tid < 64) {
        float s = fcd_b[0];
        for (int j = 0; j < 128; ++j) s = fmaf(hs[tid * 129 + j], fcd_w[j], s);
        directout[b0 + tid] = s;
    }

    // h2 = relu(fc2 h + b2); out index j*64+bb -> j wave-uniform (scalar weight loads)
    for (int out = tid; out < 128 * 64; out += 256) {
        int j = out >> 6, bb = out & 63;
        float s = fc2_b[j];
        const float* wr = fc2_w + j * 128;
        #pragma unroll 8
        for (int k = 0; k < 128; ++k) s = fmaf(hs[bb * 129 + k], wr[k], s);
        h2s[bb * 129 + j] = fmaxf(s, 0.f);
    }
    __syncthreads();

    // x3 = fc3 h2 + b3 (100 outputs) -> o0out[j][b] layout for coalesced phase-A reads
    for (int out = tid; out < 100 * 64; out += 256) {
        int j = out >> 6, bb = out & 63;
        float s = fc3_b[j];
        const float* wr = fc3_w + j * 128;
        #pragma unroll 8
        for (int k = 0; k < 128; ++k) s = fmaf(h2s[bb * 129 + k], wr[k], s);
        o0out[j * BATCH + b0 + bb] = s;
    }
}

// ---------------------------------------------------------------------------
// Phase A: oscillator scan. One wave = 64 batch lanes x OCNT oscillators.
// No barriers, no LDS; constants are wave-uniform (scalar loads).
// ---------------------------------------------------------------------------
template <int OCNT>
__device__ __forceinline__ void osc_body(const float* __restrict__ pc,
                                         const float* __restrict__ o0init,
                                         float* __restrict__ tp,
                                         int ostart, int b) {
    float s0[OCNT], s1[OCNT];
    #pragma unroll
    for (int i = 0; i < OCNT; ++i) {
        s0[i] = o0init[(2 * (ostart + i)) * BATCH + b];
        s1[i] = o0init[(2 * (ostart + i) + 1) * BATCH + b];
    }
    for (int step = 0; step < STEPS; ++step) {
        float tqx = 0.f, tqy = 0.f;
        #pragma unroll
        for (int i = 0; i < OCNT; ++i) {
            const float* p = pc + (ostart + i) * 240;
            float o0 = s0[i], o1 = s1[i];
            float d0x = 0.f, d0y = 0.f, d1x = 0.f, d1y = 0.f;
            #pragma unroll
            for (int n2 = 0; n2 < 20; ++n2) {
                const float* cp = p + n2 * 12;
                float4 q0 = *(const float4*)(cp);      // e0x e0y e1x e1y
                float4 q1 = *(const float4*)(cp + 4);  // obx oby d0x d0y
                float4 q2 = *(const float4*)(cp + 8);  // d1x d1y w4x w4y
                float ax = fmaxf(fmaf(o0, q0.x, fmaf(o1, q0.z, q1.x)), 0.f);
                float ay = fmaxf(fmaf(o0, q0.y, fmaf(o1, q0.w, q1.y)), 0.f);
                tqx = fmaf(ax, q2.z, tqx);
                tqy = fmaf(ay, q2.w, tqy);
                d0x = fmaf(ax, q1.z, d0x);
                d0y = fmaf(ay, q1.w, d0y);
                d1x = fmaf(ax, q2.x, d1x);
                d1y = fmaf(ay, q2.y, d1y);
            }
            s0[i] = fmaf(DT, d0x + d0y, s0[i]);
            s1[i] = fmaf(DT, d1x + d1y, s1[i]);
        }
        tp[step * BATCH] = tqx + tqy;
    }
}

__global__ __launch_bounds__(64) void osc_kernel(const float* __restrict__ pc,
                                                 const float* __restrict__ o0init,
                                                 float* __restrict__ tpart) {
    int og = blockIdx.x & 7;
    int bg = blockIdx.x >> 3;
    int b = bg * 64 + threadIdx.x;
    float* tp = tpart + og * (STEPS * BATCH) + b;
    if (og < 2)
        osc_body<7>(pc, o0init, tp, og * 7, b);
    else
        osc_body<6>(pc, o0init, tp, 14 + (og - 2) * 6, b);
}

// ---------------------------------------------------------------------------
// Phase B: reduce torque partials, integrate pendulum, write outputs.
// ---------------------------------------------------------------------------
__global__ __launch_bounds__(256) void pend_kernel(const float* __restrict__ x,
                                                   const float* __restrict__ tpart,
                                                   const float* __restrict__ direct,
                                                   const float* __restrict__ fc4_b,
                                                   float* __restrict__ out) {
    int b = blockIdx.x * 256 + threadIdx.x;
    float theta = x[2 * b];
    float omega = 0.f;
    float base = direct[b] + fc4_b[0];
    float* out_l = out;                       // (100, 8192, 2)
    float* out_t = out + STEPS * BATCH * 2;   // (100, 8192)
    for (int s = 0; s < STEPS; ++s) {
        float tq = base;
        #pragma unroll
        for (int g = 0; g < OG; ++g) tq += tpart[(g * STEPS + s) * BATCH + b];
        float alpha = tq - __sinf(theta) - 0.1f * omega;   // old theta, old omega
        theta = fmaf(DT, omega, theta);                    // uses old omega
        omega = fmaf(DT, alpha, omega);
        out_l[(s * BATCH + b) * 2]     = theta;
        out_l[(s * BATCH + b) * 2 + 1] = omega;
        out_t[s * BATCH + b] = tq;
    }
}

extern "C" void kernel_launch(void* const* d_in, const int* in_sizes, int n_in,
                              void* d_out, int out_size, void* d_ws, size_t ws_size,
                              hipStream_t stream) {
    const float* x     = (const float*)d_in[0];
    const float* fc1_w = (const float*)d_in[1];
    const float* fc1_b = (const float*)d_in[2];
    const float* fc2_w = (const float*)d_in[3];
    const float* fc2_b = (const float*)d_in[4];
    const float* fc3_w = (const float*)d_in[5];
    const float* fc3_b = (const float*)d_in[6];
    const float* fcd_w = (const float*)d_in[7];
    const float* fcd_b = (const float*)d_in[8];
    const float* enc   = (const float*)d_in[9];
    const float* obias = (const float*)d_in[10];
    const float* dec   = (const float*)d_in[11];
    const float* fc4_w = (const float*)d_in[12];
    const float* fc4_b = (const float*)d_in[13];
    float* out = (float*)d_out;
    float* ws = (float*)d_ws;

    float* pc      = ws + WS_PC;
    float* direct  = ws + WS_DIRECT;
    float* o0      = ws + WS_O0;
    float* tpart   = ws + WS_TPART;

    hipLaunchKernelGGL(pack_consts, dim3(8), dim3(256), 0, stream,
                       enc, obias, dec, fc4_w, pc);
    hipLaunchKernelGGL(mlp_kernel, dim3(128), dim3(256), 0, stream,
                       x, fc1_w, fc1_b, fc2_w, fc2_b, fc3_w, fc3_b,
                       fcd_w, fcd_b, o0, direct);
    hipLaunchKernelGGL(osc_kernel, dim3(1024), dim3(64), 0, stream,
                       pc, o0, tpart);
    hipLaunchKernelGGL(pend_kernel, dim3(BATCH / 256), dim3(256), 0, stream,
                       x, tpart, direct, fc4_b, out);
}

// Round 2
// 1382.334 us; speedup vs baseline: 1.0832x; 1.0832x over previous
//
#include <hip/hip_runtime.h>

#define N_OSC 50
#define N_PER 40
#define DT 0.01f
#define STEPS 100
#define BATCH 8192

// ws layout (float offsets)
#define WS_PC     0        // 50*240 = 12000 packed consts
#define WS_DIRECT 12288    // 8192
#define WS_O0     20480    // 100*8192
#define WS_TORQ   839680   // 100*8192 torque accumulator

// ---------------------------------------------------------------------------
// Pack per-(osc,n) constants into AoS pairs: for each osc, 20 chunks of 12:
// [e0x,e0y, e1x,e1y, obx,oby, d0x,d0y, d1x,d1y, w4x,w4y]
// ---------------------------------------------------------------------------
__global__ void pack_consts(const float* __restrict__ enc,
                            const float* __restrict__ obias,
                            const float* __restrict__ dec,
                            const float* __restrict__ fc4_w,
                            float* __restrict__ pc) {
    int idx = blockIdx.x * blockDim.x + threadIdx.x;
    if (idx >= N_OSC * N_PER) return;
    int o = idx / N_PER, n = idx % N_PER;
    int n2 = n >> 1, h = n & 1;
    float* base = pc + o * 240 + n2 * 12;
    base[0 + h]  = enc[o * 80 + 2 * n + 0];
    base[2 + h]  = enc[o * 80 + 2 * n + 1];
    base[4 + h]  = obias[o * 40 + n];
    base[6 + h]  = dec[o * 80 + n];          // dec[o][0][n]
    base[8 + h]  = dec[o * 80 + 40 + n];     // dec[o][1][n]
    base[10 + h] = fc4_w[o * 40 + n];
}

// Zero the torque accumulator (ws is poisoned 0xAA before every launch).
__global__ __launch_bounds__(256) void torq_zero(float* __restrict__ torq) {
    int i = blockIdx.x * 256 + threadIdx.x;
    ((float4*)torq)[i] = make_float4(0.f, 0.f, 0.f, 0.f);
}

// ---------------------------------------------------------------------------
// MLP prologue: h = relu(fc1), direct = fcd(h), h2 = relu(fc2 h), x3 = fc3 h2
// Block = 256 threads handles 64 batch elements.
// ---------------------------------------------------------------------------
__global__ __launch_bounds__(256) void mlp_kernel(
    const float* __restrict__ x,
    const float* __restrict__ fc1_w, const float* __restrict__ fc1_b,
    const float* __restrict__ fc2_w, const float* __restrict__ fc2_b,
    const float* __restrict__ fc3_w, const float* __restrict__ fc3_b,
    const float* __restrict__ fcd_w, const float* __restrict__ fcd_b,
    float* __restrict__ o0out, float* __restrict__ directout) {
    __shared__ float hs[64 * 129];
    __shared__ float h2s[64 * 129];
    int tid = threadIdx.x;
    int b0 = blockIdx.x * 64;

    // h (relu(fc1 x + b1)) : 64x128 outputs
    for (int idx = tid; idx < 64 * 128; idx += 256) {
        int bb = idx >> 7, j = idx & 127;
        float x0 = x[(b0 + bb) * 2], x1 = x[(b0 + bb) * 2 + 1];
        float v = fmaf(x0, fc1_w[j * 2], fmaf(x1, fc1_w[j * 2 + 1], fc1_b[j]));
        hs[bb * 129 + j] = fmaxf(v, 0.f);
    }
    __syncthreads();

    // direct = h . fcd_w + fcd_b (one thread per b)
    if (tid < 64) {
        float s = fcd_b[0];
        for (int j = 0; j < 128; ++j) s = fmaf(hs[tid * 129 + j], fcd_w[j], s);
        directout[b0 + tid] = s;
    }

    // h2 = relu(fc2 h + b2); j wave-uniform -> scalar weight loads
    for (int out = tid; out < 128 * 64; out += 256) {
        int j = out >> 6, bb = out & 63;
        float s = fc2_b[j];
        const float* wr = fc2_w + j * 128;
        #pragma unroll 8
        for (int k = 0; k < 128; ++k) s = fmaf(hs[bb * 129 + k], wr[k], s);
        h2s[bb * 129 + j] = fmaxf(s, 0.f);
    }
    __syncthreads();

    // x3 = fc3 h2 + b3 (100 outputs) -> o0out[j][b] for coalesced phase-A reads
    for (int out = tid; out < 100 * 64; out += 256) {
        int j = out >> 6, bb = out & 63;
        float s = fc3_b[j];
        const float* wr = fc3_w + j * 128;
        #pragma unroll 8
        for (int k = 0; k < 128; ++k) s = fmaf(h2s[bb * 129 + k], wr[k], s);
        o0out[j * BATCH + b0 + bb] = s;
    }
}

// ---------------------------------------------------------------------------
// Phase A: oscillator scan. ONE OSCILLATOR PER WAVE: 128 b-groups x 50 osc =
// 6400 single-wave blocks (~6.5 waves/SIMD, all co-resident). Per-step torque
// partial is fire-and-forget global atomicAdd into torq[step][b].
// ---------------------------------------------------------------------------
__global__ __launch_bounds__(64) void osc_kernel(const float* __restrict__ pc,
                                                 const float* __restrict__ o0init,
                                                 float* __restrict__ torq) {
    int blk = blockIdx.x;
    int bg = blk / N_OSC;          // 0..127
    int osc = blk - bg * N_OSC;    // 0..49
    int b = bg * 64 + threadIdx.x;
    const float* __restrict__ p = pc + osc * 240;

    float s0 = o0init[(2 * osc) * BATCH + b];
    float s1 = o0init[(2 * osc + 1) * BATCH + b];

    for (int step = 0; step < STEPS; ++step) {
        float tqx = 0.f, tqy = 0.f;
        float d0x = 0.f, d0y = 0.f, d1x = 0.f, d1y = 0.f;
        #pragma unroll
        for (int n2 = 0; n2 < 20; ++n2) {
            const float* cp = p + n2 * 12;
            float4 q0 = *(const float4*)(cp);      // e0x e0y e1x e1y
            float4 q1 = *(const float4*)(cp + 4);  // obx oby d0x d0y
            float4 q2 = *(const float4*)(cp + 8);  // d1x d1y w4x w4y
            float ax = fmaxf(fmaf(s0, q0.x, fmaf(s1, q0.z, q1.x)), 0.f);
            float ay = fmaxf(fmaf(s0, q0.y, fmaf(s1, q0.w, q1.y)), 0.f);
            tqx = fmaf(ax, q2.z, tqx);
            tqy = fmaf(ay, q2.w, tqy);
            d0x = fmaf(ax, q1.z, d0x);
            d0y = fmaf(ay, q1.w, d0y);
            d1x = fmaf(ax, q2.x, d1x);
            d1y = fmaf(ay, q2.y, d1y);
        }
        s0 = fmaf(DT, d0x + d0y, s0);
        s1 = fmaf(DT, d1x + d1y, s1);
        atomicAdd(&torq[step * BATCH + b], tqx + tqy);
    }
}

// ---------------------------------------------------------------------------
// Phase B: integrate pendulum from reduced torque, write outputs.
// ---------------------------------------------------------------------------
__global__ __launch_bounds__(256) void pend_kernel(const float* __restrict__ x,
                                                   const float* __restrict__ torq,
                                                   const float* __restrict__ direct,
                                                   const float* __restrict__ fc4_b,
                                                   float* __restrict__ out) {
    int b = blockIdx.x * 256 + threadIdx.x;
    float theta = x[2 * b];
    float omega = 0.f;
    float base = direct[b] + fc4_b[0];
    float* out_l = out;                       // (100, 8192, 2)
    float* out_t = out + STEPS * BATCH * 2;   // (100, 8192)
    #pragma unroll 2
    for (int s = 0; s < STEPS; ++s) {
        float tq = base + torq[s * BATCH + b];
        float alpha = tq - __sinf(theta) - 0.1f * omega;   // old theta, old omega
        theta = fmaf(DT, omega, theta);                    // uses old omega
        omega = fmaf(DT, alpha, omega);
        out_l[(s * BATCH + b) * 2]     = theta;
        out_l[(s * BATCH + b) * 2 + 1] = omega;
        out_t[s * BATCH + b] = tq;
    }
}

extern "C" void kernel_launch(void* const* d_in, const int* in_sizes, int n_in,
                              void* d_out, int out_size, void* d_ws, size_t ws_size,
                              hipStream_t stream) {
    const float* x     = (const float*)d_in[0];
    const float* fc1_w = (const float*)d_in[1];
    const float* fc1_b = (const float*)d_in[2];
    const float* fc2_w = (const float*)d_in[3];
    const float* fc2_b = (const float*)d_in[4];
    const float* fc3_w = (const float*)d_in[5];
    const float* fc3_b = (const float*)d_in[6];
    const float* fcd_w = (const float*)d_in[7];
    const float* fcd_b = (const float*)d_in[8];
    const float* enc   = (const float*)d_in[9];
    const float* obias = (const float*)d_in[10];
    const float* dec   = (const float*)d_in[11];
    const float* fc4_w = (const float*)d_in[12];
    const float* fc4_b = (const float*)d_in[13];
    float* out = (float*)d_out;
    float* ws = (float*)d_ws;

    float* pc      = ws + WS_PC;
    float* direct  = ws + WS_DIRECT;
    float* o0      = ws + WS_O0;
    float* torq    = ws + WS_TORQ;

    hipLaunchKernelGGL(pack_consts, dim3(8), dim3(256), 0, stream,
                       enc, obias, dec, fc4_w, pc);
    hipLaunchKernelGGL(torq_zero, dim3(STEPS * BATCH / 4 / 256), dim3(256), 0, stream,
                       torq);
    hipLaunchKernelGGL(mlp_kernel, dim3(128), dim3(256), 0, stream,
                       x, fc1_w, fc1_b, fc2_w, fc2_b, fc3_w, fc3_b,
                       fcd_w, fcd_b, o0, direct);
    hipLaunchKernelGGL(osc_kernel, dim3(128 * N_OSC), dim3(64), 0, stream,
                       pc, o0, torq);
    hipLaunchKernelGGL(pend_kernel, dim3(BATCH / 256), dim3(256), 0, stream,
                       x, torq, direct, fc4_b, out);
}

// Round 3
// 658.889 us; speedup vs baseline: 2.2726x; 2.0980x over previous
//
#include <hip/hip_runtime.h>

#define N_OSC 50
#define N_PER 40
#define DT 0.01f
#define STEPS 100
#define BATCH 8192

typedef float v2f __attribute__((ext_vector_type(2)));

static __device__ __forceinline__ v2f fma2(v2f a, v2f b, v2f c) {
    return __builtin_elementwise_fma(a, b, c);
}

// ws layout (float offsets)
#define WS_PC     0        // 50*240 = 12000 packed consts
#define WS_DIRECT 12288    // 8192
#define WS_O0     20480    // 100*8192
#define WS_TORQ   839680   // 100*8192 torque accumulator

// ---------------------------------------------------------------------------
// Packed consts per osc (stride 240 floats):
//   [0..79]    E: chunk i -> (e0 of unit 2i, e0 of 2i+1, e1 of 2i, e1 of 2i+1)
//   [80..159]  D: chunk i -> (d0 of 2i, d0 of 2i+1, d1 of 2i, d1 of 2i+1)
//   [160..199] W: chunk i -> (w4 of 2i, w4 of 2i+1)
//   [200..239] OB: obias[n] in natural order
// ---------------------------------------------------------------------------
__global__ void pack_consts(const float* __restrict__ enc,
                            const float* __restrict__ obias,
                            const float* __restrict__ dec,
                            const float* __restrict__ fc4_w,
                            float* __restrict__ pc) {
    int idx = blockIdx.x * blockDim.x + threadIdx.x;
    if (idx >= N_OSC * N_PER) return;
    int o = idx / N_PER, n = idx % N_PER;
    int i = n >> 1, h = n & 1;
    float* base = pc + o * 240;
    base[4 * i + h]           = enc[o * 80 + 2 * n + 0];   // e0
    base[4 * i + 2 + h]       = enc[o * 80 + 2 * n + 1];   // e1
    base[80 + 4 * i + h]      = dec[o * 80 + n];           // dec[o][0][n]
    base[80 + 4 * i + 2 + h]  = dec[o * 80 + 40 + n];      // dec[o][1][n]
    base[160 + 2 * i + h]     = fc4_w[o * 40 + n];
    base[200 + n]             = obias[o * 40 + n];
}

// Zero the torque accumulator (ws is poisoned 0xAA before every launch).
__global__ __launch_bounds__(256) void torq_zero(float* __restrict__ torq) {
    int i = blockIdx.x * 256 + threadIdx.x;
    ((float4*)torq)[i] = make_float4(0.f, 0.f, 0.f, 0.f);
}

// ---------------------------------------------------------------------------
// MLP prologue (unchanged).
// ---------------------------------------------------------------------------
__global__ __launch_bounds__(256) void mlp_kernel(
    const float* __restrict__ x,
    const float* __restrict__ fc1_w, const float* __restrict__ fc1_b,
    const float* __restrict__ fc2_w, const float* __restrict__ fc2_b,
    const float* __restrict__ fc3_w, const float* __restrict__ fc3_b,
    const float* __restrict__ fcd_w, const float* __restrict__ fcd_b,
    float* __restrict__ o0out, float* __restrict__ directout) {
    __shared__ float hs[64 * 129];
    __shared__ float h2s[64 * 129];
    int tid = threadIdx.x;
    int b0 = blockIdx.x * 64;

    for (int idx = tid; idx < 64 * 128; idx += 256) {
        int bb = idx >> 7, j = idx & 127;
        float x0 = x[(b0 + bb) * 2], x1 = x[(b0 + bb) * 2 + 1];
        float v = fmaf(x0, fc1_w[j * 2], fmaf(x1, fc1_w[j * 2 + 1], fc1_b[j]));
        hs[bb * 129 + j] = fmaxf(v, 0.f);
    }
    __syncthreads();

    if (tid < 64) {
        float s = fcd_b[0];
        for (int j = 0; j < 128; ++j) s = fmaf(hs[tid * 129 + j], fcd_w[j], s);
        directout[b0 + tid] = s;
    }

    for (int out = tid; out < 128 * 64; out += 256) {
        int j = out >> 6, bb = out & 63;
        float s = fc2_b[j];
        const float* wr = fc2_w + j * 128;
        #pragma unroll 8
        for (int k = 0; k < 128; ++k) s = fmaf(hs[bb * 129 + k], wr[k], s);
        h2s[bb * 129 + j] = fmaxf(s, 0.f);
    }
    __syncthreads();

    for (int out = tid; out < 100 * 64; out += 256) {
        int j = out >> 6, bb = out & 63;
        float s = fc3_b[j];
        const float* wr = fc3_w + j * 128;
        #pragma unroll 8
        for (int k = 0; k < 128; ++k) s = fmaf(h2s[bb * 129 + k], wr[k], s);
        o0out[j * BATCH + b0 + bb] = s;
    }
}

// ---------------------------------------------------------------------------
// Phase A: one oscillator per wave; ALL constants VGPR/SGPR-resident across
// the 100-step loop (zero loads in the hot loop). x/y unit pairs packed as
// float2 to get v_pk_fma_f32. 6400 single-wave blocks, 2 waves/SIMD resident.
// ---------------------------------------------------------------------------
__global__ __launch_bounds__(64, 2) void osc_kernel(const float* __restrict__ pc,
                                                    const float* __restrict__ o0init,
                                                    float* __restrict__ torq) {
    int blk = blockIdx.x;
    int bg = blk / N_OSC;          // 0..127
    int osc = blk - bg * N_OSC;    // 0..49
    int b = bg * 64 + threadIdx.x;
    const float* __restrict__ base = pc + osc * 240;

    // Load constants once: 200 floats -> VGPRs (wave-uniform, broadcast loads).
    v2f e0[20], e1[20], d0c[20], d1c[20], wc[20];
    #pragma unroll
    for (int i = 0; i < 20; ++i) {
        float4 q = *(const float4*)(base + 4 * i);
        e0[i] = (v2f){q.x, q.y};
        e1[i] = (v2f){q.z, q.w};
    }
    #pragma unroll
    for (int i = 0; i < 20; ++i) {
        float4 q = *(const float4*)(base + 80 + 4 * i);
        d0c[i] = (v2f){q.x, q.y};
        d1c[i] = (v2f){q.z, q.w};
    }
    #pragma unroll
    for (int i = 0; i < 10; ++i) {
        float4 q = *(const float4*)(base + 160 + 4 * i);
        wc[2 * i]     = (v2f){q.x, q.y};
        wc[2 * i + 1] = (v2f){q.z, q.w};
    }
    // obias -> SGPRs via readfirstlane (wave-uniform), so every packed FMA
    // has at most one scalar operand.
    float ob[40];
    #pragma unroll
    for (int n = 0; n < 40; ++n) {
        union { float f; int i; } u;
        u.f = base[200 + n];
        u.i = __builtin_amdgcn_readfirstlane(u.i);
        ob[n] = u.f;
    }

    float s0 = o0init[(2 * osc) * BATCH + b];
    float s1 = o0init[(2 * osc + 1) * BATCH + b];

    for (int step = 0; step < STEPS; ++step) {
        v2f o0p = (v2f){s0, s0};
        v2f o1p = (v2f){s1, s1};
        v2f tq = (v2f){0.f, 0.f};
        v2f D0 = (v2f){0.f, 0.f};
        v2f D1 = (v2f){0.f, 0.f};
        #pragma unroll
        for (int i = 0; i < 20; ++i) {
            v2f obp = (v2f){ob[2 * i], ob[2 * i + 1]};
            v2f a = fma2(o0p, e0[i], fma2(o1p, e1[i], obp));
            a = __builtin_elementwise_max(a, (v2f){0.f, 0.f});
            tq = fma2(a, wc[i], tq);
            D0 = fma2(a, d0c[i], D0);
            D1 = fma2(a, d1c[i], D1);
        }
        s0 = fmaf(DT, D0.x + D0.y, s0);
        s1 = fmaf(DT, D1.x + D1.y, s1);
        atomicAdd(&torq[step * BATCH + b], tq.x + tq.y);
    }
}

// ---------------------------------------------------------------------------
// Phase B: integrate pendulum; software-prefetch torq to hide load latency.
// ---------------------------------------------------------------------------
__global__ __launch_bounds__(64) void pend_kernel(const float* __restrict__ x,
                                                  const float* __restrict__ torq,
                                                  const float* __restrict__ direct,
                                                  const float* __restrict__ fc4_b,
                                                  float* __restrict__ out) {
    int b = blockIdx.x * 64 + threadIdx.x;
    float theta = x[2 * b];
    float omega = 0.f;
    float base = direct[b] + fc4_b[0];
    float* out_l = out;                       // (100, 8192, 2)
    float* out_t = out + STEPS * BATCH * 2;   // (100, 8192)
    float pf[4];
    #pragma unroll
    for (int j = 0; j < 4; ++j) pf[j] = torq[j * BATCH + b];
    #pragma unroll 4
    for (int s = 0; s < STEPS; ++s) {
        float tq = base + pf[s & 3];
        if (s + 4 < STEPS) pf[s & 3] = torq[(s + 4) * BATCH + b];
        float alpha = tq - __sinf(theta) - 0.1f * omega;   // old theta, old omega
        theta = fmaf(DT, omega, theta);                    // uses old omega
        omega = fmaf(DT, alpha, omega);
        out_l[(s * BATCH + b) * 2]     = theta;
        out_l[(s * BATCH + b) * 2 + 1] = omega;
        out_t[s * BATCH + b] = tq;
    }
}

extern "C" void kernel_launch(void* const* d_in, const int* in_sizes, int n_in,
                              void* d_out, int out_size, void* d_ws, size_t ws_size,
                              hipStream_t stream) {
    const float* x     = (const float*)d_in[0];
    const float* fc1_w = (const float*)d_in[1];
    const float* fc1_b = (const float*)d_in[2];
    const float* fc2_w = (const float*)d_in[3];
    const float* fc2_b = (const float*)d_in[4];
    const float* fc3_w = (const float*)d_in[5];
    const float* fc3_b = (const float*)d_in[6];
    const float* fcd_w = (const float*)d_in[7];
    const float* fcd_b = (const float*)d_in[8];
    const float* enc   = (const float*)d_in[9];
    const float* obias = (const float*)d_in[10];
    const float* dec   = (const float*)d_in[11];
    const float* fc4_w = (const float*)d_in[12];
    const float* fc4_b = (const float*)d_in[13];
    float* out = (float*)d_out;
    float* ws = (float*)d_ws;

    float* pc      = ws + WS_PC;
    float* direct  = ws + WS_DIRECT;
    float* o0      = ws + WS_O0;
    float* torq    = ws + WS_TORQ;

    hipLaunchKernelGGL(pack_consts, dim3(8), dim3(256), 0, stream,
                       enc, obias, dec, fc4_w, pc);
    hipLaunchKernelGGL(torq_zero, dim3(STEPS * BATCH / 4 / 256), dim3(256), 0, stream,
                       torq);
    hipLaunchKernelGGL(mlp_kernel, dim3(128), dim3(256), 0, stream,
                       x, fc1_w, fc1_b, fc2_w, fc2_b, fc3_w, fc3_b,
                       fcd_w, fcd_b, o0, direct);
    hipLaunchKernelGGL(osc_kernel, dim3(128 * N_OSC), dim3(64), 0, stream,
                       pc, o0, torq);
    hipLaunchKernelGGL(pend_kernel, dim3(BATCH / 64), dim3(64), 0, stream,
                       x, torq, direct, fc4_b, out);
}

// Round 4
// 428.994 us; speedup vs baseline: 3.4904x; 1.5359x over previous
//
#include <hip/hip_runtime.h>

#define N_OSC 50
#define N_PER 40
#define DT 0.01f
#define STEPS 100
#define BATCH 8192

typedef float v2f __attribute__((ext_vector_type(2)));

static __device__ __forceinline__ v2f fma2(v2f a, v2f b, v2f c) {
    return __builtin_elementwise_fma(a, b, c);
}

// ws layout (float offsets)
#define WS_PC     0        // 50*240 = 12000 packed consts
#define WS_DIRECT 12288    // 8192
#define WS_O0     20480    // 100*8192
#define WS_TORQ   839680   // 100*8192 torque accumulator

// ---------------------------------------------------------------------------
// Packed consts per osc (stride 240 floats):
//   [0..79]    E: chunk i -> (e0 of unit 2i, e0 of 2i+1, e1 of 2i, e1 of 2i+1)
//   [80..159]  D: chunk i -> (d0 of 2i, d0 of 2i+1, d1 of 2i, d1 of 2i+1)
//   [160..199] W: chunk i -> (w4 of 2i, w4 of 2i+1)
//   [200..239] OB: obias[n] in natural order
// ---------------------------------------------------------------------------
__global__ void pack_consts(const float* __restrict__ enc,
                            const float* __restrict__ obias,
                            const float* __restrict__ dec,
                            const float* __restrict__ fc4_w,
                            float* __restrict__ pc) {
    int idx = blockIdx.x * blockDim.x + threadIdx.x;
    if (idx >= N_OSC * N_PER) return;
    int o = idx / N_PER, n = idx % N_PER;
    int i = n >> 1, h = n & 1;
    float* base = pc + o * 240;
    base[4 * i + h]           = enc[o * 80 + 2 * n + 0];   // e0
    base[4 * i + 2 + h]       = enc[o * 80 + 2 * n + 1];   // e1
    base[80 + 4 * i + h]      = dec[o * 80 + n];           // dec[o][0][n]
    base[80 + 4 * i + 2 + h]  = dec[o * 80 + 40 + n];      // dec[o][1][n]
    base[160 + 2 * i + h]     = fc4_w[o * 40 + n];
    base[200 + n]             = obias[o * 40 + n];
}

// Zero the torque accumulator (ws is poisoned 0xAA before every launch).
__global__ __launch_bounds__(256) void torq_zero(float* __restrict__ torq) {
    int i = blockIdx.x * 256 + threadIdx.x;
    ((float4*)torq)[i] = make_float4(0.f, 0.f, 0.f, 0.f);
}

// ---------------------------------------------------------------------------
// MLP prologue. 128 blocks x 512 threads, 64 batch rows per block.
// fc2/fc3: wave-uniform j (readfirstlane) -> s_load weights; one
// ds_read_b128 of the h-row feeds 16 FMAs (4 j-outputs x 4 k).
// ---------------------------------------------------------------------------
__global__ __launch_bounds__(512) void mlp_kernel(
    const float* __restrict__ x,
    const float* __restrict__ fc1_w, const float* __restrict__ fc1_b,
    const float* __restrict__ fc2_w, const float* __restrict__ fc2_b,
    const float* __restrict__ fc3_w, const float* __restrict__ fc3_b,
    const float* __restrict__ fcd_w, const float* __restrict__ fcd_b,
    float* __restrict__ o0out, float* __restrict__ directout) {
    __shared__ float hs[64 * 132];
    __shared__ float h2s[64 * 132];
    int tid = threadIdx.x;
    int lane = tid & 63;
    int wv = __builtin_amdgcn_readfirstlane(tid >> 6);  // 0..7, wave-uniform
    int b0 = blockIdx.x * 64;

    // fc1: h = relu(x @ fc1_w.T + b1), 64x128 outputs
    for (int idx = tid; idx < 64 * 128; idx += 512) {
        int bb = idx >> 7, j = idx & 127;
        float x0 = x[(b0 + bb) * 2], x1 = x[(b0 + bb) * 2 + 1];
        float v = fmaf(x0, fc1_w[j * 2], fmaf(x1, fc1_w[j * 2 + 1], fc1_b[j]));
        hs[bb * 132 + j] = fmaxf(v, 0.f);
    }
    __syncthreads();

    // direct = h . fcd_w + fcd_b (wave 0, one lane per b)
    if (tid < 64) {
        float s = fcd_b[0];
        #pragma unroll 8
        for (int k = 0; k < 128; k += 4) {
            float4 h4 = *(const float4*)&hs[tid * 132 + k];
            float4 w4 = *(const float4*)&fcd_w[k];
            s = fmaf(h4.x, w4.x, fmaf(h4.y, w4.y, fmaf(h4.z, w4.z, fmaf(h4.w, w4.w, s))));
        }
        directout[b0 + tid] = s;
    }

    // fc2: h2 = relu(h @ fc2_w.T + b2). 8 waves x 4 passes x 4 j = 128 j.
    for (int pass = 0; pass < 4; ++pass) {
        int j0 = wv * 16 + pass * 4;
        float a0 = fc2_b[j0], a1 = fc2_b[j0 + 1], a2 = fc2_b[j0 + 2], a3 = fc2_b[j0 + 3];
        const float* w0 = fc2_w + j0 * 128;
        const float* w1 = w0 + 128;
        const float* w2 = w0 + 256;
        const float* w3 = w0 + 384;
        #pragma unroll 8
        for (int k = 0; k < 128; k += 4) {
            float4 h4 = *(const float4*)&hs[lane * 132 + k];
            float4 q0 = *(const float4*)&w0[k];
            float4 q1 = *(const float4*)&w1[k];
            float4 q2 = *(const float4*)&w2[k];
            float4 q3 = *(const float4*)&w3[k];
            a0 = fmaf(h4.x, q0.x, fmaf(h4.y, q0.y, fmaf(h4.z, q0.z, fmaf(h4.w, q0.w, a0))));
            a1 = fmaf(h4.x, q1.x, fmaf(h4.y, q1.y, fmaf(h4.z, q1.z, fmaf(h4.w, q1.w, a1))));
            a2 = fmaf(h4.x, q2.x, fmaf(h4.y, q2.y, fmaf(h4.z, q2.z, fmaf(h4.w, q2.w, a2))));
            a3 = fmaf(h4.x, q3.x, fmaf(h4.y, q3.y, fmaf(h4.z, q3.z, fmaf(h4.w, q3.w, a3))));
        }
        h2s[lane * 132 + j0]     = fmaxf(a0, 0.f);
        h2s[lane * 132 + j0 + 1] = fmaxf(a1, 0.f);
        h2s[lane * 132 + j0 + 2] = fmaxf(a2, 0.f);
        h2s[lane * 132 + j0 + 3] = fmaxf(a3, 0.f);
    }
    __syncthreads();

    // fc3: x3 = h2 @ fc3_w.T + b3 (100 outputs) -> o0out[j][b]
    for (int pass = 0; pass < 4; ++pass) {
        int j0 = pass * 32 + wv * 4;
        if (j0 >= 100) continue;
        float a0 = fc3_b[j0], a1 = fc3_b[j0 + 1], a2 = fc3_b[j0 + 2], a3 = fc3_b[j0 + 3];
        const float* w0 = fc3_w + j0 * 128;
        const float* w1 = w0 + 128;
        const float* w2 = w0 + 256;
        const float* w3 = w0 + 384;
        #pragma unroll 8
        for (int k = 0; k < 128; k += 4) {
            float4 h4 = *(const float4*)&h2s[lane * 132 + k];
            float4 q0 = *(const float4*)&w0[k];
            float4 q1 = *(const float4*)&w1[k];
            float4 q2 = *(const float4*)&w2[k];
            float4 q3 = *(const float4*)&w3[k];
            a0 = fmaf(h4.x, q0.x, fmaf(h4.y, q0.y, fmaf(h4.z, q0.z, fmaf(h4.w, q0.w, a0))));
            a1 = fmaf(h4.x, q1.x, fmaf(h4.y, q1.y, fmaf(h4.z, q1.z, fmaf(h4.w, q1.w, a1))));
            a2 = fmaf(h4.x, q2.x, fmaf(h4.y, q2.y, fmaf(h4.z, q2.z, fmaf(h4.w, q2.w, a2))));
            a3 = fmaf(h4.x, q3.x, fmaf(h4.y, q3.y, fmaf(h4.z, q3.z, fmaf(h4.w, q3.w, a3))));
        }
        o0out[(j0)     * BATCH + b0 + lane] = a0;
        o0out[(j0 + 1) * BATCH + b0 + lane] = a1;
        o0out[(j0 + 2) * BATCH + b0 + lane] = a2;
        o0out[(j0 + 3) * BATCH + b0 + lane] = a3;
    }
}

// ---------------------------------------------------------------------------
// Phase A: one oscillator per wave. Constants delivered LDS -> ds_read ->
// VGPRs (LDS loads are "divergent" to the compiler, so they CANNOT be
// scalarized back to SGPR reloads). ~222 VGPRs, 2 waves/SIMD, ZERO memory
// ops in the 100-step hot loop. obias -> SGPRs via readfirstlane.
// ---------------------------------------------------------------------------
__global__ __launch_bounds__(64, 2) void osc_kernel(const float* __restrict__ pc,
                                                    const float* __restrict__ o0init,
                                                    float* __restrict__ torq) {
    __shared__ float cs[240];
    int blk = blockIdx.x;
    int bg = blk / N_OSC;          // 0..127
    int osc = blk - bg * N_OSC;    // 0..49
    int tid = threadIdx.x;
    int b = bg * 64 + tid;

    if (tid < 60)
        ((float4*)cs)[tid] = ((const float4*)(pc + osc * 240))[tid];
    __syncthreads();

    // LDS -> VGPR-resident constants (100 v2f = 200 VGPRs)
    v2f e0[20], e1[20], d0c[20], d1c[20], wc[20];
    #pragma unroll
    for (int i = 0; i < 20; ++i) {
        e0[i]  = *(const v2f*)(cs + 4 * i);
        e1[i]  = *(const v2f*)(cs + 4 * i + 2);
        d0c[i] = *(const v2f*)(cs + 80 + 4 * i);
        d1c[i] = *(const v2f*)(cs + 80 + 4 * i + 2);
    }
    #pragma unroll
    for (int i = 0; i < 20; ++i) wc[i] = *(const v2f*)(cs + 160 + 2 * i);

    // obias -> SGPRs (wave-uniform)
    float ob[40];
    #pragma unroll
    for (int n = 0; n < 40; ++n) {
        union { float f; int i; } u;
        u.f = cs[200 + n];
        u.i = __builtin_amdgcn_readfirstlane(u.i);
        ob[n] = u.f;
    }

    float s0 = o0init[(2 * osc) * BATCH + b];
    float s1 = o0init[(2 * osc + 1) * BATCH + b];

    for (int step = 0; step < STEPS; ++step) {
        v2f o0p = (v2f){s0, s0};
        v2f o1p = (v2f){s1, s1};
        v2f tq = (v2f){0.f, 0.f};
        v2f D0 = (v2f){0.f, 0.f};
        v2f D1 = (v2f){0.f, 0.f};
        #pragma unroll
        for (int i = 0; i < 20; ++i) {
            v2f obp = (v2f){ob[2 * i], ob[2 * i + 1]};
            v2f a = fma2(o0p, e0[i], fma2(o1p, e1[i], obp));
            a = __builtin_elementwise_max(a, (v2f){0.f, 0.f});
            tq = fma2(a, wc[i], tq);
            D0 = fma2(a, d0c[i], D0);
            D1 = fma2(a, d1c[i], D1);
        }
        s0 = fmaf(DT, D0.x + D0.y, s0);
        s1 = fmaf(DT, D1.x + D1.y, s1);
        atomicAdd(&torq[step * BATCH + b], tq.x + tq.y);
    }
}

// ---------------------------------------------------------------------------
// Phase B: integrate pendulum; prefetch torq; packed float2 state store.
// ---------------------------------------------------------------------------
__global__ __launch_bounds__(64) void pend_kernel(const float* __restrict__ x,
                                                  const float* __restrict__ torq,
                                                  const float* __restrict__ direct,
                                                  const float* __restrict__ fc4_b,
                                                  float* __restrict__ out) {
    int b = blockIdx.x * 64 + threadIdx.x;
    float theta = x[2 * b];
    float omega = 0.f;
    float base = direct[b] + fc4_b[0];
    float2* out_l = (float2*)out;             // (100, 8192, 2)
    float* out_t = out + STEPS * BATCH * 2;   // (100, 8192)
    float pf[4];
    #pragma unroll
    for (int j = 0; j < 4; ++j) pf[j] = torq[j * BATCH + b];
    #pragma unroll 4
    for (int s = 0; s < STEPS; ++s) {
        float tq = base + pf[s & 3];
        if (s + 4 < STEPS) pf[s & 3] = torq[(s + 4) * BATCH + b];
        float alpha = tq - __sinf(theta) - 0.1f * omega;   // old theta, old omega
        theta = fmaf(DT, omega, theta);                    // uses old omega
        omega = fmaf(DT, alpha, omega);
        out_l[s * BATCH + b] = make_float2(theta, omega);
        out_t[s * BATCH + b] = tq;
    }
}

extern "C" void kernel_launch(void* const* d_in, const int* in_sizes, int n_in,
                              void* d_out, int out_size, void* d_ws, size_t ws_size,
                              hipStream_t stream) {
    const float* x     = (const float*)d_in[0];
    const float* fc1_w = (const float*)d_in[1];
    const float* fc1_b = (const float*)d_in[2];
    const float* fc2_w = (const float*)d_in[3];
    const float* fc2_b = (const float*)d_in[4];
    const float* fc3_w = (const float*)d_in[5];
    const float* fc3_b = (const float*)d_in[6];
    const float* fcd_w = (const float*)d_in[7];
    const float* fcd_b = (const float*)d_in[8];
    const float* enc   = (const float*)d_in[9];
    const float* obias = (const float*)d_in[10];
    const float* dec   = (const float*)d_in[11];
    const float* fc4_w = (const float*)d_in[12];
    const float* fc4_b = (const float*)d_in[13];
    float* out = (float*)d_out;
    float* ws = (float*)d_ws;

    float* pc      = ws + WS_PC;
    float* direct  = ws + WS_DIRECT;
    float* o0      = ws + WS_O0;
    float* torq    = ws + WS_TORQ;

    hipLaunchKernelGGL(pack_consts, dim3(8), dim3(256), 0, stream,
                       enc, obias, dec, fc4_w, pc);
    hipLaunchKernelGGL(torq_zero, dim3(STEPS * BATCH / 4 / 256), dim3(256), 0, stream,
                       torq);
    hipLaunchKernelGGL(mlp_kernel, dim3(128), dim3(512), 0, stream,
                       x, fc1_w, fc1_b, fc2_w, fc2_b, fc3_w, fc3_b,
                       fcd_w, fcd_b, o0, direct);
    hipLaunchKernelGGL(osc_kernel, dim3(128 * N_OSC), dim3(64), 0, stream,
                       pc, o0, torq);
    hipLaunchKernelGGL(pend_kernel, dim3(BATCH / 64), dim3(64), 0, stream,
                       x, torq, direct, fc4_b, out);
}

// Round 5
// 414.201 us; speedup vs baseline: 3.6151x; 1.0357x over previous
//
#include <hip/hip_runtime.h>

#define N_OSC 50
#define N_PER 40
#define DT 0.01f
#define STEPS 100
#define BATCH 8192

typedef float v2f __attribute__((ext_vector_type(2)));

static __device__ __forceinline__ v2f fma2(v2f a, v2f b, v2f c) {
    return __builtin_elementwise_fma(a, b, c);
}

// ws layout (float offsets)
#define WS_PC     0        // 50*240 = 12000 packed consts
#define WS_DIRECT 12288    // 8192
#define WS_O0     20480    // 100*8192
#define WS_TORQ   839680   // 100*8192 torque accumulator

// ---------------------------------------------------------------------------
// Prep: zero torq accumulator + pack per-osc constants.
// Packed consts per osc (stride 240 floats):
//   [0..79]    E: chunk i -> (e0 of unit 2i, e0 of 2i+1, e1 of 2i, e1 of 2i+1)
//   [80..159]  D: chunk i -> (d0 of 2i, d0 of 2i+1, d1 of 2i, d1 of 2i+1)
//   [160..199] W: chunk i -> (w4 of 2i, w4 of 2i+1)
//   [200..239] OB: obias[n] in natural order
// ---------------------------------------------------------------------------
__global__ __launch_bounds__(256) void prep_kernel(
    const float* __restrict__ enc, const float* __restrict__ obias,
    const float* __restrict__ dec, const float* __restrict__ fc4_w,
    float* __restrict__ pc, float* __restrict__ torq) {
    int idx = blockIdx.x * 256 + threadIdx.x;
    ((float4*)torq)[idx] = make_float4(0.f, 0.f, 0.f, 0.f);   // 800*256*4 = 819200
    if (idx < N_OSC * N_PER) {
        int o = idx / N_PER, n = idx - o * N_PER;
        int i = n >> 1, h = n & 1;
        float* base = pc + o * 240;
        base[4 * i + h]           = enc[o * 80 + 2 * n + 0];   // e0
        base[4 * i + 2 + h]       = enc[o * 80 + 2 * n + 1];   // e1
        base[80 + 4 * i + h]      = dec[o * 80 + n];           // dec[o][0][n]
        base[80 + 4 * i + 2 + h]  = dec[o * 80 + 40 + n];      // dec[o][1][n]
        base[160 + 2 * i + h]     = fc4_w[o * 40 + n];
        base[200 + n]             = obias[o * 40 + n];
    }
}

// ---------------------------------------------------------------------------
// MLP prologue. 256 blocks x 256 threads, 32 batch rows per block -> all CUs.
// half-wave hw = tid>>5 owns j-quads (weight addrs uniform per half-wave);
// lane bb = tid&31 owns a batch row; one float4 LDS read feeds 16 FMAs.
// ---------------------------------------------------------------------------
__global__ __launch_bounds__(256) void mlp_kernel(
    const float* __restrict__ x,
    const float* __restrict__ fc1_w, const float* __restrict__ fc1_b,
    const float* __restrict__ fc2_w, const float* __restrict__ fc2_b,
    const float* __restrict__ fc3_w, const float* __restrict__ fc3_b,
    const float* __restrict__ fcd_w, const float* __restrict__ fcd_b,
    float* __restrict__ o0out, float* __restrict__ directout) {
    __shared__ float hs[32 * 132];
    __shared__ float h2s[32 * 132];
    int tid = threadIdx.x;
    int bb = tid & 31;
    int hw = tid >> 5;             // 0..7
    int b0 = blockIdx.x * 32;

    // fc1: h = relu(x @ fc1_w.T + b1), 32x128 outputs (16 per thread)
    for (int idx = tid; idx < 32 * 128; idx += 256) {
        int r = idx >> 7, j = idx & 127;
        float x0 = x[(b0 + r) * 2], x1 = x[(b0 + r) * 2 + 1];
        float v = fmaf(x0, fc1_w[j * 2], fmaf(x1, fc1_w[j * 2 + 1], fc1_b[j]));
        hs[r * 132 + j] = fmaxf(v, 0.f);
    }
    __syncthreads();

    // direct = h . fcd_w + fcd_b
    if (tid < 32) {
        float s = fcd_b[0];
        #pragma unroll 8
        for (int k = 0; k < 128; k += 4) {
            float4 h4 = *(const float4*)&hs[tid * 132 + k];
            float4 w4 = *(const float4*)&fcd_w[k];
            s = fmaf(h4.x, w4.x, fmaf(h4.y, w4.y, fmaf(h4.z, w4.z, fmaf(h4.w, w4.w, s))));
        }
        directout[b0 + tid] = s;
    }

    // fc2: h2 = relu(h @ fc2_w.T + b2). 8 hw x 4 passes x 4 j = 128 j.
    for (int pass = 0; pass < 4; ++pass) {
        int j0 = hw * 16 + pass * 4;
        float a0 = fc2_b[j0], a1 = fc2_b[j0 + 1], a2 = fc2_b[j0 + 2], a3 = fc2_b[j0 + 3];
        const float* w0 = fc2_w + j0 * 128;
        const float* w1 = w0 + 128;
        const float* w2 = w0 + 256;
        const float* w3 = w0 + 384;
        #pragma unroll 8
        for (int k = 0; k < 128; k += 4) {
            float4 h4 = *(const float4*)&hs[bb * 132 + k];
            float4 q0 = *(const float4*)&w0[k];
            float4 q1 = *(const float4*)&w1[k];
            float4 q2 = *(const float4*)&w2[k];
            float4 q3 = *(const float4*)&w3[k];
            a0 = fmaf(h4.x, q0.x, fmaf(h4.y, q0.y, fmaf(h4.z, q0.z, fmaf(h4.w, q0.w, a0))));
            a1 = fmaf(h4.x, q1.x, fmaf(h4.y, q1.y, fmaf(h4.z, q1.z, fmaf(h4.w, q1.w, a1))));
            a2 = fmaf(h4.x, q2.x, fmaf(h4.y, q2.y, fmaf(h4.z, q2.z, fmaf(h4.w, q2.w, a2))));
            a3 = fmaf(h4.x, q3.x, fmaf(h4.y, q3.y, fmaf(h4.z, q3.z, fmaf(h4.w, q3.w, a3))));
        }
        h2s[bb * 132 + j0]     = fmaxf(a0, 0.f);
        h2s[bb * 132 + j0 + 1] = fmaxf(a1, 0.f);
        h2s[bb * 132 + j0 + 2] = fmaxf(a2, 0.f);
        h2s[bb * 132 + j0 + 3] = fmaxf(a3, 0.f);
    }
    __syncthreads();

    // fc3: x3 = h2 @ fc3_w.T + b3 (100 outputs) -> o0out[j][b]
    for (int pass = 0; pass < 4; ++pass) {
        int j0 = pass * 32 + hw * 4;
        if (j0 >= 100) continue;
        float a0 = fc3_b[j0], a1 = fc3_b[j0 + 1], a2 = fc3_b[j0 + 2], a3 = fc3_b[j0 + 3];
        const float* w0 = fc3_w + j0 * 128;
        const float* w1 = w0 + 128;
        const float* w2 = w0 + 256;
        const float* w3 = w0 + 384;
        #pragma unroll 8
        for (int k = 0; k < 128; k += 4) {
            float4 h4 = *(const float4*)&h2s[bb * 132 + k];
            float4 q0 = *(const float4*)&w0[k];
            float4 q1 = *(const float4*)&w1[k];
            float4 q2 = *(const float4*)&w2[k];
            float4 q3 = *(const float4*)&w3[k];
            a0 = fmaf(h4.x, q0.x, fmaf(h4.y, q0.y, fmaf(h4.z, q0.z, fmaf(h4.w, q0.w, a0))));
            a1 = fmaf(h4.x, q1.x, fmaf(h4.y, q1.y, fmaf(h4.z, q1.z, fmaf(h4.w, q1.w, a1))));
            a2 = fmaf(h4.x, q2.x, fmaf(h4.y, q2.y, fmaf(h4.z, q2.z, fmaf(h4.w, q2.w, a2))));
            a3 = fmaf(h4.x, q3.x, fmaf(h4.y, q3.y, fmaf(h4.z, q3.z, fmaf(h4.w, q3.w, a3))));
        }
        o0out[(j0)     * BATCH + b0 + bb] = a0;
        o0out[(j0 + 1) * BATCH + b0 + bb] = a1;
        o0out[(j0 + 2) * BATCH + b0 + bb] = a2;
        o0out[(j0 + 3) * BATCH + b0 + bb] = a3;
    }
}

// ---------------------------------------------------------------------------
// Phase A: one oscillator per wave. Constants: LDS -> VGPRs ONCE, then
// PINNED in registers via opaque inline asm (compiler cannot rematerialize
// the post-asm values from LDS -> must keep ~200 VGPRs live). Hot loop is
// pure v_pk_fma_f32, zero memory ops. obias -> SGPRs via readfirstlane.
// ---------------------------------------------------------------------------
__global__ __launch_bounds__(64, 2) void osc_kernel(const float* __restrict__ pc,
                                                    const float* __restrict__ o0init,
                                                    float* __restrict__ torq) {
    __shared__ float cs[240];
    int blk = blockIdx.x;
    int bg = blk / N_OSC;          // 0..127
    int osc = blk - bg * N_OSC;    // 0..49
    int tid = threadIdx.x;
    int b = bg * 64 + tid;

    if (tid < 60)
        ((float4*)cs)[tid] = ((const float4*)(pc + osc * 240))[tid];
    __syncthreads();

    // LDS -> VGPR-resident constants (100 v2f = 200 VGPRs)
    v2f e0[20], e1[20], d0c[20], d1c[20], wc[20];
    #pragma unroll
    for (int i = 0; i < 20; ++i) {
        e0[i]  = *(const v2f*)(cs + 4 * i);
        e1[i]  = *(const v2f*)(cs + 4 * i + 2);
        d0c[i] = *(const v2f*)(cs + 80 + 4 * i);
        d1c[i] = *(const v2f*)(cs + 80 + 4 * i + 2);
        wc[i]  = *(const v2f*)(cs + 160 + 2 * i);
    }
    // Pin: make each constant opaque so it MUST stay in VGPRs.
    #pragma unroll
    for (int i = 0; i < 20; ++i) {
        asm volatile("" : "+v"(e0[i]));
        asm volatile("" : "+v"(e1[i]));
        asm volatile("" : "+v"(d0c[i]));
        asm volatile("" : "+v"(d1c[i]));
        asm volatile("" : "+v"(wc[i]));
    }

    // obias -> SGPRs (wave-uniform)
    float ob[40];
    #pragma unroll
    for (int n = 0; n < 40; ++n) {
        union { float f; int i; } u;
        u.f = cs[200 + n];
        u.i = __builtin_amdgcn_readfirstlane(u.i);
        ob[n] = u.f;
    }

    float s0 = o0init[(2 * osc) * BATCH + b];
    float s1 = o0init[(2 * osc + 1) * BATCH + b];

    for (int step = 0; step < STEPS; ++step) {
        v2f o0p = (v2f){s0, s0};
        v2f o1p = (v2f){s1, s1};
        v2f tq = (v2f){0.f, 0.f};
        v2f D0 = (v2f){0.f, 0.f};
        v2f D1 = (v2f){0.f, 0.f};
        #pragma unroll
        for (int i = 0; i < 20; ++i) {
            v2f obp = (v2f){ob[2 * i], ob[2 * i + 1]};
            v2f a = fma2(o0p, e0[i], fma2(o1p, e1[i], obp));
            a = __builtin_elementwise_max(a, (v2f){0.f, 0.f});
            tq = fma2(a, wc[i], tq);
            D0 = fma2(a, d0c[i], D0);
            D1 = fma2(a, d1c[i], D1);
        }
        s0 = fmaf(DT, D0.x + D0.y, s0);
        s1 = fmaf(DT, D1.x + D1.y, s1);
        atomicAdd(&torq[step * BATCH + b], tq.x + tq.y);
    }
}

// ---------------------------------------------------------------------------
// Phase B: integrate pendulum; prefetch torq; packed float2 state store.
// ---------------------------------------------------------------------------
__global__ __launch_bounds__(256) void pend_kernel(const float* __restrict__ x,
                                                   const float* __restrict__ torq,
                                                   const float* __restrict__ direct,
                                                   const float* __restrict__ fc4_b,
                                                   float* __restrict__ out) {
    int b = blockIdx.x * 256 + threadIdx.x;
    float theta = x[2 * b];
    float omega = 0.f;
    float base = direct[b] + fc4_b[0];
    float2* out_l = (float2*)out;             // (100, 8192, 2)
    float* out_t = out + STEPS * BATCH * 2;   // (100, 8192)
    float pf[4];
    #pragma unroll
    for (int j = 0; j < 4; ++j) pf[j] = torq[j * BATCH + b];
    #pragma unroll 4
    for (int s = 0; s < STEPS; ++s) {
        float tq = base + pf[s & 3];
        if (s + 4 < STEPS) pf[s & 3] = torq[(s + 4) * BATCH + b];
        float alpha = tq - __sinf(theta) - 0.1f * omega;   // old theta, old omega
        theta = fmaf(DT, omega, theta);                    // uses old omega
        omega = fmaf(DT, alpha, omega);
        out_l[s * BATCH + b] = make_float2(theta, omega);
        out_t[s * BATCH + b] = tq;
    }
}

extern "C" void kernel_launch(void* const* d_in, const int* in_sizes, int n_in,
                              void* d_out, int out_size, void* d_ws, size_t ws_size,
                              hipStream_t stream) {
    const float* x     = (const float*)d_in[0];
    const float* fc1_w = (const float*)d_in[1];
    const float* fc1_b = (const float*)d_in[2];
    const float* fc2_w = (const float*)d_in[3];
    const float* fc2_b = (const float*)d_in[4];
    const float* fc3_w = (const float*)d_in[5];
    const float* fc3_b = (const float*)d_in[6];
    const float* fcd_w = (const float*)d_in[7];
    const float* fcd_b = (const float*)d_in[8];
    const float* enc   = (const float*)d_in[9];
    const float* obias = (const float*)d_in[10];
    const float* dec   = (const float*)d_in[11];
    const float* fc4_w = (const float*)d_in[12];
    const float* fc4_b = (const float*)d_in[13];
    float* out = (float*)d_out;
    float* ws = (float*)d_ws;

    float* pc      = ws + WS_PC;
    float* direct  = ws + WS_DIRECT;
    float* o0      = ws + WS_O0;
    float* torq    = ws + WS_TORQ;

    hipLaunchKernelGGL(prep_kernel, dim3(STEPS * BATCH / 4 / 256), dim3(256), 0, stream,
                       enc, obias, dec, fc4_w, pc, torq);
    hipLaunchKernelGGL(mlp_kernel, dim3(256), dim3(256), 0, stream,
                       x, fc1_w, fc1_b, fc2_w, fc2_b, fc3_w, fc3_b,
                       fcd_w, fcd_b, o0, direct);
    hipLaunchKernelGGL(osc_kernel, dim3(128 * N_OSC), dim3(64), 0, stream,
                       pc, o0, torq);
    hipLaunchKernelGGL(pend_kernel, dim3(BATCH / 256), dim3(256), 0, stream,
                       x, torq, direct, fc4_b, out);
}